// Round 6
// baseline (358.645 us; speedup 1.0000x reference)
//
#include <hip/hip_runtime.h>

// Problem constants (fixed by the reference: x,y are (3000, 800, 8) f32)
#define NT   3000          // time samples per trace
#define NK   2999          // NT-1 (cdf length)
#define NTR  6400          // traces (800*8); trace n element t at X[t*NTR+n]
#define TRIW 4498500.0f    // sum_{i=1..2999} i
#define FINF 3.4e38f

// ===================== NEW PATH (transposed merge-path) =====================
#define TSTR 3008          // padded per-trace row stride (floats) = 47*64
#define CB   47            // 64-wide time chunks

__device__ __forceinline__ float wave_incl_scan(float v, int lane) {
    #pragma unroll
    for (int d = 1; d < 64; d <<= 1) {
        float t = __shfl_up(v, d);
        if (lane >= d) v += t;
    }
    return v;
}
__device__ __forceinline__ float wave_red_add(float v) {
    #pragma unroll
    for (int d = 1; d < 64; d <<= 1) v += __shfl_xor(v, d);
    return v;
}
__device__ __forceinline__ float wave_red_min(float v) {
    #pragma unroll
    for (int d = 1; d < 64; d <<= 1) v = fminf(v, __shfl_xor(v, d));
    return v;
}

// kT: LDS-tiled transpose of s-midpoints into [trace][time] + fused chunk
// stats (per-chunk min of raw a, per-chunk weighted sum s*(NK-j)).
// grid (100 n-tiles, 47 j-tiles, 2 arrays), 256 threads.
__global__ __launch_bounds__(256) void kT(
    const float* __restrict__ X, const float* __restrict__ Y,
    float* __restrict__ sTx, float* __restrict__ sTy,
    float* __restrict__ mnx, float* __restrict__ mny,
    float* __restrict__ wsx, float* __restrict__ wsy)
{
    __shared__ float t[65][65];        // [j-row][n-col], pad for transposed read
    const int lane = threadIdx.x & 63;
    const int wv   = threadIdx.x >> 6;
    const int n0 = blockIdx.x * 64;
    const int j0 = blockIdx.y * 64;
    const int z  = blockIdx.z;
    const float* __restrict__ src = z ? Y : X;
    float* __restrict__ dst = z ? sTy : sTx;
    float* __restrict__ mnA = z ? mny : mnx;
    float* __restrict__ wsA = z ? wsy : wsx;

    #pragma unroll
    for (int i = 0; i < 17; ++i) {
        const int r = wv + 4 * i;
        if (r < 65) {
            const int jr = j0 + r;
            if (jr < NT) t[r][lane] = src[(size_t)jr * NTR + n0 + lane];
        }
    }
    __syncthreads();

    const int j = j0 + lane;
    const bool vs = (j < NK);          // s[j] defined
    const bool va = (j < NT);          // a[j] defined
    const float w = vs ? (float)(NK - j) : 0.f;

    for (int rr = 0; rr < 16; ++rr) {
        const int row = wv * 16 + rr;  // local trace index
        const float a0 = t[lane][row];
        const float a1 = t[lane + 1][row];
        const float s  = vs ? 0.5f * (a0 + a1) : 0.f;
        dst[(size_t)(n0 + row) * TSTR + j0 + lane] = s;   // pads get 0
        const float ws = wave_red_add(s * w);
        const float mv = wave_red_min(va ? a0 : FINF);
        if (lane == 0) {
            wsA[blockIdx.y * NTR + n0 + row] = ws;
            mnA[blockIdx.y * NTR + n0 + row] = mv;
        }
    }
}

// kB2: per trace: joint min over 47 chunk-mins, S = sum(ws) - mind*TRIW.
__global__ __launch_bounds__(256) void kB2(
    const float* __restrict__ mnx, const float* __restrict__ mny,
    const float* __restrict__ wsx, const float* __restrict__ wsy,
    float* __restrict__ mindA, float* __restrict__ SsA, float* __restrict__ SoA)
{
    const int n = blockIdx.x * 256 + threadIdx.x;
    float mn = FINF, sx = 0.f, sy = 0.f;
    for (int c = 0; c < CB; ++c) {
        const int o = c * NTR + n;
        mn = fminf(mn, fminf(mnx[o], mny[o]));
        sx += wsx[o]; sy += wsy[o];
    }
    mindA[n] = mn;
    SsA[n] = sx - mn * TRIW;
    SoA[n] = sy - mn * TRIW;
}

// kC2: one wave per trace. Syn CDF in 64-wide batches (contiguous load +
// wave scan); obs CDF as a 64-value register window (contiguous load + scan);
// rank = m0 + 6-step shfl binary search. Invariant: positions < m0 all have
// ov < every pending/future target (targets monotone, window advances only
// when all satisfiable lanes are resolved).
__global__ __launch_bounds__(256) void kC2(
    const float* __restrict__ sTx, const float* __restrict__ sTy,
    const float* __restrict__ mindA, const float* __restrict__ SsA,
    const float* __restrict__ SoA, float* __restrict__ partial)
{
    const int lane = threadIdx.x & 63;
    const int wv   = threadIdx.x >> 6;
    const int n = blockIdx.x * 4 + wv;

    const float mind = mindA[n];
    const float Ss = SsA[n];
    const float So = SoA[n];
    const float* __restrict__ sx_row = sTx + (size_t)n * TSTR;
    const float* __restrict__ sy_row = sTy + (size_t)n * TSTR;

    int   m0 = 0;
    float co = 0.f;                    // raw obs cumsum through m0-1
    float ov;                          // obs'[m0+lane] * Ss (FINF past end)

    #define REFILL() do {                                                   \
        const int mm = m0 + lane;                                           \
        float v_ = (mm < NK) ? sy_row[mm] : 0.f;                            \
        float pf_ = wave_incl_scan(v_, lane);                               \
        ov = (mm < NK) ? (co + pf_ - (float)(mm + 1) * mind) * Ss : FINF;   \
        co += __shfl(pf_, 63);                                              \
    } while (0)

    REFILL();

    float cs = 0.f, acc = 0.f;
    for (int b = 0; b < CB; ++b) {
        const int j = b * 64 + lane;
        const bool valid = (j < NK);
        float v = valid ? sx_row[j] : 0.f;
        float pf = wave_incl_scan(v, lane);
        const float synp = cs + pf - (float)(j + 1) * mind;  // cdf'_syn[j]
        cs += __shfl(pf, 63);
        const float target = valid ? synp * So : -FINF;

        bool pend = true;
        int idx = 0;
        while (true) {
            const float ov_top = __shfl(ov, 63);
            // uniform-participation binary count of window values < target
            int lo = 0;
            #pragma unroll
            for (int s = 32; s; s >>= 1) {
                const float pv = __shfl(ov, lo + s - 1);
                if (pv < target) lo += s;
            }
            if (pend && (target <= ov_top)) { idx = m0 + lo; pend = false; }
            if (__all(!pend)) break;
            m0 += 64;
            REFILL();                   // wave-uniform advance
        }
        if (valid) {
            const float diff = (float)(j + 1 - idx);
            acc = fmaf(diff * diff, synp, acc);
        }
    }
    #undef REFILL

    const float tot = wave_red_add(acc);
    __shared__ float red[4];
    if (lane == 0) red[wv] = tot / Ss;
    __syncthreads();
    if (threadIdx.x == 0)
        partial[blockIdx.x] = red[0] + red[1] + red[2] + red[3];
}

// kD: reduce 1600 block partials -> out[0] (no global atomics anywhere).
__global__ __launch_bounds__(256) void kD(
    const float* __restrict__ partial, float* __restrict__ out)
{
    float v = 0.f;
    for (int i = threadIdx.x; i < 1600; i += 256) v += partial[i];
    __shared__ float red[256];
    red[threadIdx.x] = v;
    __syncthreads();
    for (int s = 128; s > 0; s >>= 1) {
        if (threadIdx.x < s) red[threadIdx.x] += red[threadIdx.x + s];
        __syncthreads();
    }
    if (threadIdx.x == 0) out[0] = red[0];
}

// ===================== FALLBACK PATH (proven R3 pipeline) ===================
#define NPAIR  3200
#define FCH    64
#define FKCH   47
#define GRP    8
#define GT     64

__global__ __launch_bounds__(128) void fA(
    const float* __restrict__ X, const float* __restrict__ Y,
    float* __restrict__ offx, float* __restrict__ offy,
    float* __restrict__ cmn,
    float* __restrict__ wsxA, float* __restrict__ wsyA)
{
    const int p = blockIdx.x * 128 + threadIdx.x;
    const int n = 2 * p;
    const int c = blockIdx.y;
    const int j0 = c * FKCH;
    const int j1 = min(NK, j0 + FKCH);

    const float2* __restrict__ X2 = (const float2*)X;
    const float2* __restrict__ Y2 = (const float2*)Y;

    float2 xp = X2[j0 * NPAIR + p];
    float2 yp = Y2[j0 * NPAIR + p];
    float mn0 = fminf(xp.x, yp.x), mn1 = fminf(xp.y, yp.y);
    float sx0 = 0.f, sx1 = 0.f, sy0 = 0.f, sy1 = 0.f;
    float wx0 = 0.f, wx1 = 0.f, wy0 = 0.f, wy1 = 0.f;

    #pragma unroll 8
    for (int j = j0; j < j1; ++j) {
        const float2 xn = X2[(j + 1) * NPAIR + p];
        const float2 yn = Y2[(j + 1) * NPAIR + p];
        const float w = (float)(NK - j);
        float s;
        s = 0.5f * (xp.x + xn.x); sx0 += s; wx0 = fmaf(s, w, wx0);
        s = 0.5f * (xp.y + xn.y); sx1 += s; wx1 = fmaf(s, w, wx1);
        s = 0.5f * (yp.x + yn.x); sy0 += s; wy0 = fmaf(s, w, wy0);
        s = 0.5f * (yp.y + yn.y); sy1 += s; wy1 = fmaf(s, w, wy1);
        mn0 = fminf(mn0, fminf(xn.x, yn.x));
        mn1 = fminf(mn1, fminf(xn.y, yn.y));
        xp = xn; yp = yn;
    }

    const int o = c * NTR + n;
    *(float2*)&offx[o] = make_float2(sx0, sx1);
    *(float2*)&offy[o] = make_float2(sy0, sy1);
    *(float2*)&cmn[o]  = make_float2(mn0, mn1);
    atomicAdd(&wsxA[n], wx0); atomicAdd(&wsxA[n + 1], wx1);
    atomicAdd(&wsyA[n], wy0); atomicAdd(&wsyA[n + 1], wy1);
}

__global__ __launch_bounds__(256) void fB(
    float* __restrict__ offx, float* __restrict__ offy,
    const float* __restrict__ cmn,
    const float* __restrict__ wsxA, const float* __restrict__ wsyA,
    float* __restrict__ mindA, float* __restrict__ SsynA,
    float* __restrict__ SobsA, float* __restrict__ out)
{
    __shared__ float tA[FCH][GT + 1];
    __shared__ float tB[FCH][GT + 1];

    const int n0 = blockIdx.x * GT;
    const int tid = threadIdx.x;
    const int lane = tid & 63;
    const int crow = tid >> 6;
    if (blockIdx.x == 0 && tid == 0) out[0] = 0.0f;

    for (int c = crow; c < FCH; c += 4)
        tB[c][lane] = cmn[c * NTR + n0 + lane];
    __syncthreads();
    if (tid < GT) {
        float mn = FINF;
        for (int c = 0; c < FCH; ++c) mn = fminf(mn, tB[c][tid]);
        mindA[n0 + tid] = mn;
        SsynA[n0 + tid] = wsxA[n0 + tid] - mn * TRIW;
        SobsA[n0 + tid] = wsyA[n0 + tid] - mn * TRIW;
    }
    __syncthreads();

    for (int c = crow; c < FCH; c += 4) {
        tA[c][lane] = offx[c * NTR + n0 + lane];
        tB[c][lane] = offy[c * NTR + n0 + lane];
    }
    __syncthreads();
    if (tid < GT) {
        float rx = 0.f, ry = 0.f;
        for (int c = 0; c < FCH; ++c) {
            const float tx = tA[c][tid], ty = tB[c][tid];
            tA[c][tid] = rx; tB[c][tid] = ry;
            rx += tx; ry += ty;
        }
    }
    __syncthreads();
    for (int c = crow; c < FCH; c += 4) {
        offx[c * NTR + n0 + lane] = tA[c][lane];
        offy[c * NTR + n0 + lane] = tB[c][lane];
    }
}

__global__ __launch_bounds__(256) void fC(
    const float* __restrict__ X, const float* __restrict__ Y,
    const float* __restrict__ offx, const float* __restrict__ offy,
    const float* __restrict__ mindA, const float* __restrict__ SsynA,
    const float* __restrict__ SobsA, float* __restrict__ out)
{
    const int n = blockIdx.x * 256 + threadIdx.x;
    const int c = blockIdx.y;
    const int j0 = c * FKCH;
    const int j1 = min(NK, j0 + FKCH);

    const float mind = mindA[n];
    const float Ssyn = SsynA[n];
    const float Sobs = SobsA[n];
    const float invS = 1.0f / Ssyn;

    float cs = offx[c * NTR + n];
    float xp = X[j0 * NTR + n];
    float acc = 0.f;

    int   mbase;
    float co, ylast;
    float o[GRP];
    float co8, y8;

    #define FILL() do {                                                   \
        float yl_ = ylast, cc_ = co;                                      \
        _Pragma("unroll")                                                 \
        for (int i = 0; i < GRP; ++i) {                                   \
            const int m_ = mbase + i;                                     \
            const int ml_ = (m_ < NK) ? (m_ + 1) : NK;                    \
            const float yn_ = Y[ml_ * NTR + n];                           \
            cc_ += 0.5f * (yl_ + yn_);                                    \
            yl_ = yn_;                                                    \
            const float v_ = (cc_ - (float)(m_ + 1) * mind) * Ssyn;       \
            o[i] = (m_ < NK) ? v_ : FINF;                                 \
        }                                                                 \
        co8 = cc_; y8 = yl_;                                              \
    } while (0)

    #define COUNT(tgt, cnt) do {                                          \
        cnt = 0;                                                          \
        _Pragma("unroll")                                                 \
        for (int i = 0; i < GRP; ++i) cnt += (o[i] < (tgt)) ? 1 : 0;      \
    } while (0)

    {
        const float xn = X[(j0 + 1) * NTR + n];
        cs += 0.5f * (xp + xn); xp = xn;
        const float synp = cs - (float)(j0 + 1) * mind;
        const float target = synp * Sobs;

        int cc = 0;
        for (int c2 = min(FCH - 1, c + 2); c2 >= 1; --c2) {
            const float v = (offy[c2 * NTR + n] - (float)(c2 * FKCH) * mind) * Ssyn;
            if (v < target) { cc = c2; break; }
        }
        mbase = cc * FKCH;
        co = offy[cc * NTR + n];
        ylast = Y[mbase * NTR + n];
        FILL();
        int cnt; COUNT(target, cnt);
        while (cnt == GRP) {
            mbase += GRP; co = co8; ylast = y8;
            FILL();
            COUNT(target, cnt);
        }
        const float diff = (float)(j0 + 1 - (mbase + cnt));
        acc = fmaf(diff * diff, synp, acc);
    }

    for (int k = j0 + 1; k < j1; ++k) {
        const float xn = X[(k + 1) * NTR + n];
        cs += 0.5f * (xp + xn); xp = xn;
        const float synp = cs - (float)(k + 1) * mind;
        const float target = synp * Sobs;

        int cnt; COUNT(target, cnt);
        while (cnt == GRP) {
            mbase += GRP; co = co8; ylast = y8;
            FILL();
            COUNT(target, cnt);
        }
        const float diff = (float)(k + 1 - (mbase + cnt));
        acc = fmaf(diff * diff, synp, acc);
    }
    acc *= invS;

    #undef FILL
    #undef COUNT

    __shared__ float red[256];
    red[threadIdx.x] = acc;
    __syncthreads();
    for (int s = 128; s > 0; s >>= 1) {
        if (threadIdx.x < s) red[threadIdx.x] += red[threadIdx.x + s];
        __syncthreads();
    }
    if (threadIdx.x == 0) atomicAdd(out, red[0]);
}

// ---------------------------------------------------------------------------
extern "C" void kernel_launch(void* const* d_in, const int* in_sizes, int n_in,
                              void* d_out, int out_size, void* d_ws, size_t ws_size,
                              hipStream_t stream)
{
    const float* X = (const float*)d_in[0];
    const float* Y = (const float*)d_in[1];
    float* out = (float*)d_out;

    const size_t NEW_REQ =
        ((size_t)2 * NTR * TSTR + 4 * (size_t)CB * NTR + 3 * NTR + 1600) * 4;

    if (ws_size >= NEW_REQ) {
        float* w = (float*)d_ws;
        float* sTx = w;
        float* sTy = sTx + (size_t)NTR * TSTR;
        float* mnx = sTy + (size_t)NTR * TSTR;
        float* mny = mnx + CB * NTR;
        float* wsx = mny + CB * NTR;
        float* wsy = wsx + CB * NTR;
        float* mindA = wsy + CB * NTR;
        float* SsA = mindA + NTR;
        float* SoA = SsA + NTR;
        float* partial = SoA + NTR;

        kT<<<dim3(100, 47, 2), 256, 0, stream>>>(X, Y, sTx, sTy, mnx, mny, wsx, wsy);
        kB2<<<25, 256, 0, stream>>>(mnx, mny, wsx, wsy, mindA, SsA, SoA);
        kC2<<<1600, 256, 0, stream>>>(sTx, sTy, mindA, SsA, SoA, partial);
        kD<<<1, 256, 0, stream>>>(partial, out);
    } else {
        float* w = (float*)d_ws;
        float* offx  = w;
        float* offy  = offx + FCH * NTR;
        float* cmn   = offy + FCH * NTR;
        float* wsxA  = cmn  + FCH * NTR;
        float* wsyA  = wsxA + NTR;
        float* mindA = wsyA + NTR;
        float* SsynA = mindA + NTR;
        float* SobsA = SsynA + NTR;

        hipMemsetAsync(wsxA, 0, 2 * NTR * sizeof(float), stream);

        dim3 gA(NPAIR / 128, FCH), bA(128);
        dim3 gB(NTR / GT), bB(256);
        dim3 gC(NTR / 256, FCH), bC(256);
        fA<<<gA, bA, 0, stream>>>(X, Y, offx, offy, cmn, wsxA, wsyA);
        fB<<<gB, bB, 0, stream>>>(offx, offy, cmn, wsxA, wsyA,
                                  mindA, SsynA, SobsA, out);
        fC<<<gC, bC, 0, stream>>>(X, Y, offx, offy, mindA, SsynA, SobsA, out);
    }
}

// Round 7
// 331.683 us; speedup vs baseline: 1.0813x; 1.0813x over previous
//
#include <hip/hip_runtime.h>

// Problem constants (fixed by the reference: x,y are (3000, 800, 8) f32)
#define NT   3000          // time samples per trace
#define NK   2999          // NT-1 (cdf length)
#define NTR  6400          // traces (800*8); trace n element t at X[t*NTR+n]
#define TRIW 4498500.0f    // sum_{i=1..2999} i
#define FINF 3.4e38f

// ===================== MAIN PATH (transposed segmented merge) ===============
#define TSTR 3008          // padded per-trace row stride (floats) = 47*64
#define CB   47            // 64-wide time chunks per trace
#define NSEG 8             // merge segments per trace
#define SEGB 6             // batches per segment (last has 5)
#define GT   64            // traces per kB2 block
#define NCBLK 3200         // kC2 blocks = 6400*8/16 (16 waves/block)

__device__ __forceinline__ float wave_incl_scan(float v, int lane) {
    #pragma unroll
    for (int d = 1; d < 64; d <<= 1) {
        float t = __shfl_up(v, d);
        if (lane >= d) v += t;
    }
    return v;
}
__device__ __forceinline__ float wave_red_add(float v) {
    #pragma unroll
    for (int d = 1; d < 64; d <<= 1) v += __shfl_xor(v, d);
    return v;
}
// monotone float<->uint map for atomicMin on signed floats
__device__ __forceinline__ unsigned fmap(float f) {
    unsigned u = __float_as_uint(f);
    return (u & 0x80000000u) ? ~u : (u | 0x80000000u);
}
__device__ __forceinline__ float funmap(unsigned u) {
    u = (u & 0x80000000u) ? (u & 0x7FFFFFFFu) : ~u;
    return __uint_as_float(u);
}

// kT: LDS-tiled transpose of s-midpoints into [trace][time] + chunk stats,
// NO cross-lane ops. grid (100 n-tiles, 47 j-tiles, 2 arrays), 256 threads.
__global__ __launch_bounds__(256) void kT(
    const float* __restrict__ X, const float* __restrict__ Y,
    float* __restrict__ sTx, float* __restrict__ sTy,
    float* __restrict__ ssx, float* __restrict__ ssy,
    float* __restrict__ wsxA, float* __restrict__ wsyA,
    unsigned* __restrict__ mnUx, unsigned* __restrict__ mnUy)
{
    __shared__ float t[65][65];        // [j-row][trace-col]
    __shared__ float pS[4][GT], pW[4][GT], pM[4][GT];
    const int lane = threadIdx.x & 63;
    const int wv   = threadIdx.x >> 6;
    const int n0 = blockIdx.x * 64;
    const int j0 = blockIdx.y * 64;
    const int z  = blockIdx.z;
    const float* __restrict__ src = z ? Y : X;
    float* __restrict__ dst = z ? sTy : sTx;
    float* __restrict__ ssA = z ? ssy : ssx;
    float* __restrict__ wA  = z ? wsyA : wsxA;
    unsigned* __restrict__ mU = z ? mnUy : mnUx;

    // load 65 a-rows (coalesced: lane = trace)
    #pragma unroll
    for (int i = 0; i < 17; ++i) {
        const int r = wv + 4 * i;
        if (r < 65) {
            const int jr = j0 + r;
            if (jr < NT) t[r][lane] = src[(size_t)jr * NTR + n0 + lane];
        }
    }
    __syncthreads();

    // phase 2a: transposed write of s (lane = time, contiguous per row)
    const int j = j0 + lane;
    const bool vs = (j < NK);
    for (int rr = 0; rr < 16; ++rr) {
        const int row = wv * 16 + rr;  // local trace
        const float a0 = t[lane][row];
        const float a1 = t[lane + 1][row];
        dst[(size_t)(n0 + row) * TSTR + j0 + lane] = vs ? 0.5f * (a0 + a1) : 0.f;
    }

    // phase 2b: stats, lane = trace, serial over this wave's 16 time rows
    {
        const int r0 = wv * 16;
        float sum = 0.f, wsum = 0.f, mn = FINF;
        float aprev = t[r0][lane];
        #pragma unroll 4
        for (int rr = 0; rr < 16; ++rr) {
            const int jr = j0 + r0 + rr;
            const float anext = t[r0 + rr + 1][lane];
            if (jr < NT) mn = fminf(mn, aprev);
            if (jr < NK) {
                const float s = 0.5f * (aprev + anext);
                sum += s;
                wsum = fmaf(s, (float)(NK - jr), wsum);
            }
            aprev = anext;
        }
        pS[wv][lane] = sum; pW[wv][lane] = wsum; pM[wv][lane] = mn;
    }
    __syncthreads();
    if (threadIdx.x < GT) {
        const int l = threadIdx.x;
        const float S = pS[0][l] + pS[1][l] + pS[2][l] + pS[3][l];
        const float W = pW[0][l] + pW[1][l] + pW[2][l] + pW[3][l];
        const float M = fminf(fminf(pM[0][l], pM[1][l]), fminf(pM[2][l], pM[3][l]));
        ssA[blockIdx.y * NTR + n0 + l] = S;
        atomicAdd(&wA[n0 + l], W);
        atomicMin(&mU[n0 + l], fmap(M));
    }
}

// kB2: per-trace finalize: mind/S from atomics, exclusive scans of chunk sums
// (in place), and per-(segment,trace) conservative obs-start chunk qstA via a
// two-pointer over the 47+47 chunk boundary values. 100 blocks x 256.
__global__ __launch_bounds__(256) void kB2(
    float* __restrict__ ssx, float* __restrict__ ssy,
    const float* __restrict__ wsxA, const float* __restrict__ wsyA,
    const unsigned* __restrict__ mnUx, const unsigned* __restrict__ mnUy,
    float* __restrict__ mindA, float* __restrict__ SsA, float* __restrict__ SoA,
    unsigned char* __restrict__ qstA)
{
    __shared__ float tA[CB][GT + 1];
    __shared__ float tB[CB][GT + 1];
    const int n0 = blockIdx.x * GT;
    const int tid = threadIdx.x, lane = tid & 63, crow = tid >> 6;

    for (int c = crow; c < CB; c += 4) {
        tA[c][lane] = ssx[c * NTR + n0 + lane];
        tB[c][lane] = ssy[c * NTR + n0 + lane];
    }
    __syncthreads();

    if (tid < GT) {
        const float mn = fminf(funmap(mnUx[n0 + tid]), funmap(mnUy[n0 + tid]));
        const float Ss = wsxA[n0 + tid] - mn * TRIW;
        const float So = wsyA[n0 + tid] - mn * TRIW;
        mindA[n0 + tid] = mn; SsA[n0 + tid] = Ss; SoA[n0 + tid] = So;

        float rx = 0.f, ry = 0.f;
        for (int c = 0; c < CB; ++c) {
            const float tx = tA[c][tid], ty = tB[c][tid];
            tA[c][tid] = rx; tB[c][tid] = ry;
            rx += tx; ry += ty;
        }
        // qstart per segment: largest q with obsbnd'(q) < synbnd'(c0)
        int q = 0;
        for (int s = 0; s < NSEG; ++s) {
            const int c0 = s * SEGB;
            const float tgt = (tA[c0][tid] - (float)(c0 * 64) * mn) * So;
            while (q + 1 < CB) {
                const float ov = (tB[q + 1][tid] - (float)((q + 1) * 64) * mn) * Ss;
                if (ov < tgt) ++q; else break;
            }
            qstA[s * NTR + n0 + tid] = (unsigned char)q;
        }
    }
    __syncthreads();
    for (int c = crow; c < CB; c += 4) {       // write back exclusive scans
        ssx[c * NTR + n0 + lane] = tA[c][lane];
        ssy[c * NTR + n0 + lane] = tB[c][lane];
    }
}

// kC2: wave per (trace, segment). Contiguous 64-wide batches on both sides;
// obs kept as 64-value register window; rank via 6-step shfl binary count.
// 3200 blocks x 1024 threads (16 waves).
__global__ __launch_bounds__(1024) void kC2(
    const float* __restrict__ sTx, const float* __restrict__ sTy,
    const float* __restrict__ ssxS, const float* __restrict__ ssyS,
    const float* __restrict__ mindA, const float* __restrict__ SsA,
    const float* __restrict__ SoA, const unsigned char* __restrict__ qstA,
    float* __restrict__ partial)
{
    const int lane = threadIdx.x & 63;
    const int wv   = threadIdx.x >> 6;              // 0..15
    const int task = blockIdx.x * 16 + wv;          // 0..51199
    const int n    = task >> 3;
    const int seg  = task & (NSEG - 1);
    const int c0   = seg * SEGB;
    const int cend = min(CB, c0 + SEGB);

    const float mind = mindA[n];
    const float Ss = SsA[n];
    const float So = SoA[n];
    const float* __restrict__ sx_row = sTx + (size_t)n * TSTR;
    const float* __restrict__ sy_row = sTy + (size_t)n * TSTR;

    float cs = ssxS[c0 * NTR + n];                  // raw syn cumsum thru c0*64-1
    int   m0;
    float co, ov;
    {
        const int q = (int)qstA[seg * NTR + n];
        m0 = q * 64;
        co = ssyS[q * NTR + n];
    }

    #define REFILL() do {                                                   \
        const int mm = m0 + lane;                                           \
        float v_ = (mm < NK) ? sy_row[mm] : 0.f;                            \
        float pf_ = wave_incl_scan(v_, lane);                               \
        ov = (mm < NK) ? (co + pf_ - (float)(mm + 1) * mind) * Ss : FINF;   \
        co += __shfl(pf_, 63);                                              \
    } while (0)

    REFILL();

    float acc = 0.f;
    for (int b = c0; b < cend; ++b) {
        const int j = b * 64 + lane;
        const bool valid = (j < NK);
        float v = valid ? sx_row[j] : 0.f;
        float pf = wave_incl_scan(v, lane);
        const float synp = cs + pf - (float)(j + 1) * mind;  // cdf'_syn[j]
        cs += __shfl(pf, 63);
        const float target = valid ? synp * So : -FINF;

        bool pend = true;
        int idx = 0;
        while (true) {
            const float ov_top = __shfl(ov, 63);
            int lo = 0;
            #pragma unroll
            for (int s = 32; s; s >>= 1) {        // count of window vals < target
                const float pv = __shfl(ov, lo + s - 1);
                if (pv < target) lo += s;
            }
            if (pend && (target <= ov_top)) { idx = m0 + lo; pend = false; }
            if (__all(!pend)) break;
            m0 += 64;
            REFILL();                              // wave-uniform advance
        }
        if (valid) {
            const float diff = (float)(j + 1 - idx);
            acc = fmaf(diff * diff, synp, acc);
        }
    }
    #undef REFILL

    const float tot = wave_red_add(acc) / Ss;
    __shared__ float red[16];
    if (lane == 0) red[wv] = tot;
    __syncthreads();
    if (threadIdx.x < 64) {
        float v = (threadIdx.x < 16) ? red[threadIdx.x] : 0.f;
        #pragma unroll
        for (int d = 1; d < 16; d <<= 1) v += __shfl_xor(v, d);
        if (threadIdx.x == 0) partial[blockIdx.x] = v;
    }
}

// kD: reduce block partials -> out[0]
__global__ __launch_bounds__(256) void kD(
    const float* __restrict__ partial, float* __restrict__ out)
{
    float v = 0.f;
    for (int i = threadIdx.x; i < NCBLK; i += 256) v += partial[i];
    __shared__ float red[256];
    red[threadIdx.x] = v;
    __syncthreads();
    for (int s = 128; s > 0; s >>= 1) {
        if (threadIdx.x < s) red[threadIdx.x] += red[threadIdx.x + s];
        __syncthreads();
    }
    if (threadIdx.x == 0) out[0] = red[0];
}

// ===================== FALLBACK PATH (proven R3 pipeline) ===================
#define NPAIR  3200
#define FCH    64
#define FKCH   47
#define GRP    8

__global__ __launch_bounds__(128) void fA(
    const float* __restrict__ X, const float* __restrict__ Y,
    float* __restrict__ offx, float* __restrict__ offy,
    float* __restrict__ cmn,
    float* __restrict__ wsxA, float* __restrict__ wsyA)
{
    const int p = blockIdx.x * 128 + threadIdx.x;
    const int n = 2 * p;
    const int c = blockIdx.y;
    const int j0 = c * FKCH;
    const int j1 = min(NK, j0 + FKCH);

    const float2* __restrict__ X2 = (const float2*)X;
    const float2* __restrict__ Y2 = (const float2*)Y;

    float2 xp = X2[j0 * NPAIR + p];
    float2 yp = Y2[j0 * NPAIR + p];
    float mn0 = fminf(xp.x, yp.x), mn1 = fminf(xp.y, yp.y);
    float sx0 = 0.f, sx1 = 0.f, sy0 = 0.f, sy1 = 0.f;
    float wx0 = 0.f, wx1 = 0.f, wy0 = 0.f, wy1 = 0.f;

    #pragma unroll 8
    for (int j = j0; j < j1; ++j) {
        const float2 xn = X2[(j + 1) * NPAIR + p];
        const float2 yn = Y2[(j + 1) * NPAIR + p];
        const float w = (float)(NK - j);
        float s;
        s = 0.5f * (xp.x + xn.x); sx0 += s; wx0 = fmaf(s, w, wx0);
        s = 0.5f * (xp.y + xn.y); sx1 += s; wx1 = fmaf(s, w, wx1);
        s = 0.5f * (yp.x + yn.x); sy0 += s; wy0 = fmaf(s, w, wy0);
        s = 0.5f * (yp.y + yn.y); sy1 += s; wy1 = fmaf(s, w, wy1);
        mn0 = fminf(mn0, fminf(xn.x, yn.x));
        mn1 = fminf(mn1, fminf(xn.y, yn.y));
        xp = xn; yp = yn;
    }

    const int o = c * NTR + n;
    *(float2*)&offx[o] = make_float2(sx0, sx1);
    *(float2*)&offy[o] = make_float2(sy0, sy1);
    *(float2*)&cmn[o]  = make_float2(mn0, mn1);
    atomicAdd(&wsxA[n], wx0); atomicAdd(&wsxA[n + 1], wx1);
    atomicAdd(&wsyA[n], wy0); atomicAdd(&wsyA[n + 1], wy1);
}

__global__ __launch_bounds__(256) void fB(
    float* __restrict__ offx, float* __restrict__ offy,
    const float* __restrict__ cmn,
    const float* __restrict__ wsxA, const float* __restrict__ wsyA,
    float* __restrict__ mindA, float* __restrict__ SsynA,
    float* __restrict__ SobsA, float* __restrict__ out)
{
    __shared__ float tA[FCH][GT + 1];
    __shared__ float tB[FCH][GT + 1];

    const int n0 = blockIdx.x * GT;
    const int tid = threadIdx.x;
    const int lane = tid & 63;
    const int crow = tid >> 6;
    if (blockIdx.x == 0 && tid == 0) out[0] = 0.0f;

    for (int c = crow; c < FCH; c += 4)
        tB[c][lane] = cmn[c * NTR + n0 + lane];
    __syncthreads();
    if (tid < GT) {
        float mn = FINF;
        for (int c = 0; c < FCH; ++c) mn = fminf(mn, tB[c][tid]);
        mindA[n0 + tid] = mn;
        SsynA[n0 + tid] = wsxA[n0 + tid] - mn * TRIW;
        SobsA[n0 + tid] = wsyA[n0 + tid] - mn * TRIW;
    }
    __syncthreads();

    for (int c = crow; c < FCH; c += 4) {
        tA[c][lane] = offx[c * NTR + n0 + lane];
        tB[c][lane] = offy[c * NTR + n0 + lane];
    }
    __syncthreads();
    if (tid < GT) {
        float rx = 0.f, ry = 0.f;
        for (int c = 0; c < FCH; ++c) {
            const float tx = tA[c][tid], ty = tB[c][tid];
            tA[c][tid] = rx; tB[c][tid] = ry;
            rx += tx; ry += ty;
        }
    }
    __syncthreads();
    for (int c = crow; c < FCH; c += 4) {
        offx[c * NTR + n0 + lane] = tA[c][lane];
        offy[c * NTR + n0 + lane] = tB[c][lane];
    }
}

__global__ __launch_bounds__(256) void fC(
    const float* __restrict__ X, const float* __restrict__ Y,
    const float* __restrict__ offx, const float* __restrict__ offy,
    const float* __restrict__ mindA, const float* __restrict__ SsynA,
    const float* __restrict__ SobsA, float* __restrict__ out)
{
    const int n = blockIdx.x * 256 + threadIdx.x;
    const int c = blockIdx.y;
    const int j0 = c * FKCH;
    const int j1 = min(NK, j0 + FKCH);

    const float mind = mindA[n];
    const float Ssyn = SsynA[n];
    const float Sobs = SobsA[n];
    const float invS = 1.0f / Ssyn;

    float cs = offx[c * NTR + n];
    float xp = X[j0 * NTR + n];
    float acc = 0.f;

    int   mbase;
    float co, ylast;
    float o[GRP];
    float co8, y8;

    #define FILL() do {                                                   \
        float yl_ = ylast, cc_ = co;                                      \
        _Pragma("unroll")                                                 \
        for (int i = 0; i < GRP; ++i) {                                   \
            const int m_ = mbase + i;                                     \
            const int ml_ = (m_ < NK) ? (m_ + 1) : NK;                    \
            const float yn_ = Y[ml_ * NTR + n];                           \
            cc_ += 0.5f * (yl_ + yn_);                                    \
            yl_ = yn_;                                                    \
            const float v_ = (cc_ - (float)(m_ + 1) * mind) * Ssyn;       \
            o[i] = (m_ < NK) ? v_ : FINF;                                 \
        }                                                                 \
        co8 = cc_; y8 = yl_;                                              \
    } while (0)

    #define COUNT(tgt, cnt) do {                                          \
        cnt = 0;                                                          \
        _Pragma("unroll")                                                 \
        for (int i = 0; i < GRP; ++i) cnt += (o[i] < (tgt)) ? 1 : 0;      \
    } while (0)

    {
        const float xn = X[(j0 + 1) * NTR + n];
        cs += 0.5f * (xp + xn); xp = xn;
        const float synp = cs - (float)(j0 + 1) * mind;
        const float target = synp * Sobs;

        int cc = 0;
        for (int c2 = min(FCH - 1, c + 2); c2 >= 1; --c2) {
            const float v = (offy[c2 * NTR + n] - (float)(c2 * FKCH) * mind) * Ssyn;
            if (v < target) { cc = c2; break; }
        }
        mbase = cc * FKCH;
        co = offy[cc * NTR + n];
        ylast = Y[mbase * NTR + n];
        FILL();
        int cnt; COUNT(target, cnt);
        while (cnt == GRP) {
            mbase += GRP; co = co8; ylast = y8;
            FILL();
            COUNT(target, cnt);
        }
        const float diff = (float)(j0 + 1 - (mbase + cnt));
        acc = fmaf(diff * diff, synp, acc);
    }

    for (int k = j0 + 1; k < j1; ++k) {
        const float xn = X[(k + 1) * NTR + n];
        cs += 0.5f * (xp + xn); xp = xn;
        const float synp = cs - (float)(k + 1) * mind;
        const float target = synp * Sobs;

        int cnt; COUNT(target, cnt);
        while (cnt == GRP) {
            mbase += GRP; co = co8; ylast = y8;
            FILL();
            COUNT(target, cnt);
        }
        const float diff = (float)(k + 1 - (mbase + cnt));
        acc = fmaf(diff * diff, synp, acc);
    }
    acc *= invS;

    #undef FILL
    #undef COUNT

    __shared__ float red[256];
    red[threadIdx.x] = acc;
    __syncthreads();
    for (int s = 128; s > 0; s >>= 1) {
        if (threadIdx.x < s) red[threadIdx.x] += red[threadIdx.x + s];
        __syncthreads();
    }
    if (threadIdx.x == 0) atomicAdd(out, red[0]);
}

// ---------------------------------------------------------------------------
extern "C" void kernel_launch(void* const* d_in, const int* in_sizes, int n_in,
                              void* d_out, int out_size, void* d_ws, size_t ws_size,
                              hipStream_t stream)
{
    const float* X = (const float*)d_in[0];
    const float* Y = (const float*)d_in[1];
    float* out = (float*)d_out;

    // main-path workspace (floats): 2*NTR*TSTR + 2*CB*NTR + 4*NTR + 3*NTR
    //                               + NCBLK + NSEG*NTR/4  = ~156.7 MB
    const size_t NEW_REQ =
        ((size_t)2 * NTR * TSTR + 2 * (size_t)CB * NTR + 7 * NTR + NCBLK
         + (NSEG * NTR) / 4 + 16) * 4;

    if (ws_size >= NEW_REQ) {
        float* w = (float*)d_ws;
        float* sTx  = w;
        float* sTy  = sTx + (size_t)NTR * TSTR;
        float* ssx  = sTy + (size_t)NTR * TSTR;   // chunk sums -> scans
        float* ssy  = ssx + CB * NTR;
        float* wsxA = ssy + CB * NTR;             // [2*NTR] zeroed
        float* wsyA = wsxA + NTR;
        unsigned* mnU = (unsigned*)(wsyA + NTR);  // [2*NTR] set to 0xFF
        float* mindA = (float*)(mnU + 2 * NTR);
        float* SsA   = mindA + NTR;
        float* SoA   = SsA + NTR;
        float* partial = SoA + NTR;               // [NCBLK]
        unsigned char* qstA = (unsigned char*)(partial + NCBLK);  // [NSEG*NTR]

        hipMemsetAsync(wsxA, 0, 2 * NTR * sizeof(float), stream);
        hipMemsetAsync(mnU, 0xFF, 2 * NTR * sizeof(unsigned), stream);

        kT<<<dim3(100, 47, 2), 256, 0, stream>>>(X, Y, sTx, sTy, ssx, ssy,
                                                 wsxA, wsyA, mnU, mnU + NTR);
        kB2<<<100, 256, 0, stream>>>(ssx, ssy, wsxA, wsyA, mnU, mnU + NTR,
                                     mindA, SsA, SoA, qstA);
        kC2<<<NCBLK, 1024, 0, stream>>>(sTx, sTy, ssx, ssy,
                                        mindA, SsA, SoA, qstA, partial);
        kD<<<1, 256, 0, stream>>>(partial, out);
    } else {
        float* w = (float*)d_ws;
        float* offx  = w;
        float* offy  = offx + FCH * NTR;
        float* cmn   = offy + FCH * NTR;
        float* wsxA  = cmn  + FCH * NTR;
        float* wsyA  = wsxA + NTR;
        float* mindA = wsyA + NTR;
        float* SsynA = mindA + NTR;
        float* SobsA = SsynA + NTR;

        hipMemsetAsync(wsxA, 0, 2 * NTR * sizeof(float), stream);

        dim3 gA(NPAIR / 128, FCH), bA(128);
        dim3 gB(NTR / GT), bB(256);
        dim3 gC(NTR / 256, FCH), bC(256);
        fA<<<gA, bA, 0, stream>>>(X, Y, offx, offy, cmn, wsxA, wsyA);
        fB<<<gB, bB, 0, stream>>>(offx, offy, cmn, wsxA, wsyA,
                                  mindA, SsynA, SobsA, out);
        fC<<<gC, bC, 0, stream>>>(X, Y, offx, offy, mindA, SsynA, SobsA, out);
    }
}